// Round 1
// baseline (244.700 us; speedup 1.0000x reference)
//
#include <hip/hip_runtime.h>
#include <math.h>

// Output = segment_softmax over logits that depend ONLY on the inputs part of
// combined @ W_k (the agg part is constant per segment and cancels exactly in
// the segment softmax). So: fold wx[d][h] = sum_j Wk[d, h*64+j]*Wq[h,j] / 8,
// logit[n,h] = x[n,:] . wx[:,h], then per-segment softmax, out[h*N + n].

#define NROWS 500000
#define DIM 40
#define NSEG 2048
#define DOTD 64
#define NH 4
#define BLOCK 256
#define CACHE_ROWS 8   // per-thread cached logits -> segments up to 2048 rows fast path

__global__ __launch_bounds__(BLOCK) void seg_attn_kernel(
    const float* __restrict__ x,    // [N, 40]
    const int* __restrict__ seg,    // [N], sorted
    const float* __restrict__ Wk,   // [168, 256]
    const float* __restrict__ Wq,   // [4, 64]
    float* __restrict__ out)        // [4, N]
{
    __shared__ float wx[DIM][NH];
    __shared__ float redbuf[BLOCK / 64][NH];
    __shared__ float mshare[NH];
    __shared__ float dshare[NH];

    const int tid = (int)threadIdx.x;

    // ---- fold W_k[0:40,:] with W_q (tiny, redundant per block) ----
    if (tid < DIM * NH) {
        const int d = tid >> 2;
        const int h = tid & 3;
        const float* wkp = Wk + d * (NH * DOTD) + h * DOTD;
        const float* wqp = Wq + h * DOTD;
        float acc = 0.f;
        #pragma unroll
        for (int j = 0; j < DOTD; ++j) acc += wkp[j] * wqp[j];
        wx[d][h] = acc * 0.125f;  // fold 1/sqrt(64)
    }
    __syncthreads();

    // ---- segment bounds via binary search (uniform across block) ----
    const int s = (int)blockIdx.x;
    int lo = 0, hi = NROWS;
    while (lo < hi) { int mid = (lo + hi) >> 1; if (seg[mid] < s) lo = mid + 1; else hi = mid; }
    const int start = lo;
    hi = NROWS;
    while (lo < hi) { int mid = (lo + hi) >> 1; if (seg[mid] <= s) lo = mid + 1; else hi = mid; }
    const int end = lo;
    const int rows = end - start;
    if (rows <= 0) return;  // block-uniform exit

    // ---- pass 1: logits + local max ----
    float cache[CACHE_ROWS][NH];
    float lmax[NH];
    #pragma unroll
    for (int h = 0; h < NH; ++h) lmax[h] = -3.0e38f;

    for (int i = tid, it = 0; i < rows; i += BLOCK, ++it) {
        const float4* xr = (const float4*)(x + (size_t)(start + i) * DIM);
        float acc[NH] = {0.f, 0.f, 0.f, 0.f};
        #pragma unroll
        for (int q = 0; q < DIM / 4; ++q) {
            const float4 v = xr[q];
            #pragma unroll
            for (int h = 0; h < NH; ++h) {
                acc[h] += v.x * wx[4 * q + 0][h];
                acc[h] += v.y * wx[4 * q + 1][h];
                acc[h] += v.z * wx[4 * q + 2][h];
                acc[h] += v.w * wx[4 * q + 3][h];
            }
        }
        #pragma unroll
        for (int h = 0; h < NH; ++h) {
            if (it < CACHE_ROWS) cache[it][h] = acc[h];
            lmax[h] = fmaxf(lmax[h], acc[h]);
        }
    }

    // ---- block max reduce (4 waves) ----
    #pragma unroll
    for (int h = 0; h < NH; ++h) {
        float v = lmax[h];
        #pragma unroll
        for (int off = 32; off > 0; off >>= 1) v = fmaxf(v, __shfl_xor(v, off, 64));
        if ((tid & 63) == 0) redbuf[tid >> 6][h] = v;
    }
    __syncthreads();
    if (tid < NH) {
        mshare[tid] = fmaxf(fmaxf(redbuf[0][tid], redbuf[1][tid]),
                            fmaxf(redbuf[2][tid], redbuf[3][tid]));
    }
    __syncthreads();
    float m[NH];
    #pragma unroll
    for (int h = 0; h < NH; ++h) m[h] = mshare[h];

    // ---- pass 2: exp-sum ----
    float lsum[NH] = {0.f, 0.f, 0.f, 0.f};
    for (int i = tid, it = 0; i < rows; i += BLOCK, ++it) {
        float l[NH];
        if (it < CACHE_ROWS) {
            #pragma unroll
            for (int h = 0; h < NH; ++h) l[h] = cache[it][h];
        } else {  // cold fallback: segment longer than 2048 rows
            const float4* xr = (const float4*)(x + (size_t)(start + i) * DIM);
            float acc[NH] = {0.f, 0.f, 0.f, 0.f};
            for (int q = 0; q < DIM / 4; ++q) {
                const float4 v = xr[q];
                for (int h = 0; h < NH; ++h) {
                    acc[h] += v.x * wx[4 * q + 0][h] + v.y * wx[4 * q + 1][h]
                            + v.z * wx[4 * q + 2][h] + v.w * wx[4 * q + 3][h];
                }
            }
            for (int h = 0; h < NH; ++h) l[h] = acc[h];
        }
        #pragma unroll
        for (int h = 0; h < NH; ++h) lsum[h] += __expf(l[h] - m[h]);
    }
    __syncthreads();  // redbuf reuse guard
    #pragma unroll
    for (int h = 0; h < NH; ++h) {
        float v = lsum[h];
        #pragma unroll
        for (int off = 32; off > 0; off >>= 1) v += __shfl_xor(v, off, 64);
        if ((tid & 63) == 0) redbuf[tid >> 6][h] = v;
    }
    __syncthreads();
    if (tid < NH) {
        dshare[tid] = 1.0f / (redbuf[0][tid] + redbuf[1][tid] +
                              redbuf[2][tid] + redbuf[3][tid]);
    }
    __syncthreads();
    float rden[NH];
    #pragma unroll
    for (int h = 0; h < NH; ++h) rden[h] = dshare[h];

    // ---- pass 3: write normalized outputs ----
    for (int i = tid, it = 0; i < rows; i += BLOCK, ++it) {
        float l[NH];
        if (it < CACHE_ROWS) {
            #pragma unroll
            for (int h = 0; h < NH; ++h) l[h] = cache[it][h];
        } else {
            const float4* xr = (const float4*)(x + (size_t)(start + i) * DIM);
            float acc[NH] = {0.f, 0.f, 0.f, 0.f};
            for (int q = 0; q < DIM / 4; ++q) {
                const float4 v = xr[q];
                for (int h = 0; h < NH; ++h) {
                    acc[h] += v.x * wx[4 * q + 0][h] + v.y * wx[4 * q + 1][h]
                            + v.z * wx[4 * q + 2][h] + v.w * wx[4 * q + 3][h];
                }
            }
            for (int h = 0; h < NH; ++h) l[h] = acc[h];
        }
        const int n = start + i;
        #pragma unroll
        for (int h = 0; h < NH; ++h) {
            out[(size_t)h * NROWS + n] = __expf(l[h] - m[h]) * rden[h];
        }
    }
}

extern "C" void kernel_launch(void* const* d_in, const int* in_sizes, int n_in,
                              void* d_out, int out_size, void* d_ws, size_t ws_size,
                              hipStream_t stream) {
    const float* x  = (const float*)d_in[0];
    const int* seg  = (const int*)d_in[1];
    const float* Wk = (const float*)d_in[11];
    const float* Wq = (const float*)d_in[12];
    float* out = (float*)d_out;
    hipLaunchKernelGGL(seg_attn_kernel, dim3(NSEG), dim3(BLOCK), 0, stream,
                       x, seg, Wk, Wq, out);
}

// Round 2
// 164.055 us; speedup vs baseline: 1.4916x; 1.4916x over previous
//
#include <hip/hip_runtime.h>
#include <math.h>

// Output = segment_softmax over logits that depend ONLY on the inputs part of
// combined @ W_k: the agg(segment-mean MLP) contribution is constant within a
// segment and cancels exactly in the segment softmax (shift invariance).
// So: wx[d][h] = sum_j Wk[d, h*64+j]*Wq[h,j] / 8;  logit[n,h] = x[n,:].wx[:,h];
// per-segment softmax; out[h*N + n].
//
// 3 launches: (1) init ws (start/end=0, fold wx once), (2) coalesced boundary
// scan of seg -> start/end per segment, (3) per-segment softmax block.
// This removes the per-block binary-search pointer-chase that made round 1
// latency-bound (HBM 4.7%, VALU 5.4%, occupancy 11%).

#define NROWS 500000
#define DIM 40
#define NSEG 2048
#define DOTD 64
#define NH 4
#define BLOCK 256
#define CACHE_ROWS 2   // covers segments up to 512 rows (stat max ~310)

__global__ __launch_bounds__(BLOCK) void init_kernel(
    const float* __restrict__ Wk,   // [168, 256]
    const float* __restrict__ Wq,   // [4, 64]
    int* __restrict__ seg_start,    // [NSEG]
    int* __restrict__ seg_end,      // [NSEG]
    float* __restrict__ wxg)        // [DIM*NH], layout d*4+h
{
    const int tid = (int)(blockIdx.x * blockDim.x + threadIdx.x);
    if (tid < NSEG) { seg_start[tid] = 0; seg_end[tid] = 0; }
    if (tid < DIM * NH) {
        const int d = tid >> 2;
        const int h = tid & 3;
        const float* wkp = Wk + d * (NH * DOTD) + h * DOTD;
        const float* wqp = Wq + h * DOTD;
        float acc = 0.f;
        #pragma unroll
        for (int j = 0; j < DOTD; ++j) acc += wkp[j] * wqp[j];
        wxg[tid] = acc * 0.125f;  // fold 1/sqrt(64)
    }
}

__global__ __launch_bounds__(BLOCK) void boundary_kernel(
    const int* __restrict__ seg,    // [N], sorted
    int* __restrict__ seg_start,
    int* __restrict__ seg_end)
{
    const int n = (int)(blockIdx.x * blockDim.x + threadIdx.x);
    if (n >= NROWS) return;
    const int s = seg[n];
    if (n == 0 || seg[n - 1] != s) seg_start[s] = n;
    if (n == NROWS - 1 || seg[n + 1] != s) seg_end[s] = n + 1;
}

__global__ __launch_bounds__(BLOCK) void seg_attn_kernel(
    const float* __restrict__ x,          // [N, 40]
    const int* __restrict__ seg_start,
    const int* __restrict__ seg_end,
    const float* __restrict__ wxg,        // [DIM*NH]
    float* __restrict__ out)              // [4, N]
{
    __shared__ float wx[DIM][NH];
    __shared__ float redbuf[BLOCK / 64][NH];
    __shared__ float mshare[NH];
    __shared__ float dshare[NH];

    const int tid = (int)threadIdx.x;
    if (tid < DIM * NH) wx[tid >> 2][tid & 3] = wxg[tid];
    __syncthreads();

    const int s = (int)blockIdx.x;
    const int start = seg_start[s];       // uniform scalar loads
    const int end = seg_end[s];
    const int rows = end - start;
    if (rows <= 0) return;                // block-uniform exit

    // ---- pass 1: logits + local max ----
    float cache[CACHE_ROWS][NH];
    float lmax[NH];
    #pragma unroll
    for (int h = 0; h < NH; ++h) lmax[h] = -3.0e38f;

    for (int i = tid, it = 0; i < rows; i += BLOCK, ++it) {
        const float4* xr = (const float4*)(x + (size_t)(start + i) * DIM);
        float acc[NH] = {0.f, 0.f, 0.f, 0.f};
        #pragma unroll
        for (int q = 0; q < DIM / 4; ++q) {
            const float4 v = xr[q];
            #pragma unroll
            for (int h = 0; h < NH; ++h) {
                acc[h] += v.x * wx[4 * q + 0][h];
                acc[h] += v.y * wx[4 * q + 1][h];
                acc[h] += v.z * wx[4 * q + 2][h];
                acc[h] += v.w * wx[4 * q + 3][h];
            }
        }
        #pragma unroll
        for (int h = 0; h < NH; ++h) {
            if (it < CACHE_ROWS) cache[it][h] = acc[h];
            lmax[h] = fmaxf(lmax[h], acc[h]);
        }
    }

    // ---- block max reduce (4 waves) ----
    #pragma unroll
    for (int h = 0; h < NH; ++h) {
        float v = lmax[h];
        #pragma unroll
        for (int off = 32; off > 0; off >>= 1) v = fmaxf(v, __shfl_xor(v, off, 64));
        if ((tid & 63) == 0) redbuf[tid >> 6][h] = v;
    }
    __syncthreads();
    if (tid < NH) {
        mshare[tid] = fmaxf(fmaxf(redbuf[0][tid], redbuf[1][tid]),
                            fmaxf(redbuf[2][tid], redbuf[3][tid]));
    }
    __syncthreads();
    float m[NH];
    #pragma unroll
    for (int h = 0; h < NH; ++h) m[h] = mshare[h];

    // ---- pass 2: exp + sum; cache holds exp(l-m) afterwards ----
    float lsum[NH] = {0.f, 0.f, 0.f, 0.f};
    for (int i = tid, it = 0; i < rows; i += BLOCK, ++it) {
        float e[NH];
        if (it < CACHE_ROWS) {
            #pragma unroll
            for (int h = 0; h < NH; ++h) {
                e[h] = __expf(cache[it][h] - m[h]);
                cache[it][h] = e[h];
            }
        } else {  // cold fallback: segment longer than 512 rows
            const float4* xr = (const float4*)(x + (size_t)(start + i) * DIM);
            float acc[NH] = {0.f, 0.f, 0.f, 0.f};
            for (int q = 0; q < DIM / 4; ++q) {
                const float4 v = xr[q];
                for (int h = 0; h < NH; ++h) {
                    acc[h] += v.x * wx[4 * q + 0][h] + v.y * wx[4 * q + 1][h]
                            + v.z * wx[4 * q + 2][h] + v.w * wx[4 * q + 3][h];
                }
            }
            for (int h = 0; h < NH; ++h) e[h] = __expf(acc[h] - m[h]);
        }
        #pragma unroll
        for (int h = 0; h < NH; ++h) lsum[h] += e[h];
    }
    __syncthreads();  // redbuf reuse guard
    #pragma unroll
    for (int h = 0; h < NH; ++h) {
        float v = lsum[h];
        #pragma unroll
        for (int off = 32; off > 0; off >>= 1) v += __shfl_xor(v, off, 64);
        if ((tid & 63) == 0) redbuf[tid >> 6][h] = v;
    }
    __syncthreads();
    if (tid < NH) {
        dshare[tid] = 1.0f / (redbuf[0][tid] + redbuf[1][tid] +
                              redbuf[2][tid] + redbuf[3][tid]);
    }
    __syncthreads();
    float rden[NH];
    #pragma unroll
    for (int h = 0; h < NH; ++h) rden[h] = dshare[h];

    // ---- pass 3: write normalized outputs ----
    for (int i = tid, it = 0; i < rows; i += BLOCK, ++it) {
        float e[NH];
        if (it < CACHE_ROWS) {
            #pragma unroll
            for (int h = 0; h < NH; ++h) e[h] = cache[it][h];
        } else {
            const float4* xr = (const float4*)(x + (size_t)(start + i) * DIM);
            float acc[NH] = {0.f, 0.f, 0.f, 0.f};
            for (int q = 0; q < DIM / 4; ++q) {
                const float4 v = xr[q];
                for (int h = 0; h < NH; ++h) {
                    acc[h] += v.x * wx[4 * q + 0][h] + v.y * wx[4 * q + 1][h]
                            + v.z * wx[4 * q + 2][h] + v.w * wx[4 * q + 3][h];
                }
            }
            for (int h = 0; h < NH; ++h) e[h] = __expf(acc[h] - m[h]);
        }
        const int n = start + i;
        #pragma unroll
        for (int h = 0; h < NH; ++h) {
            out[(size_t)h * NROWS + n] = e[h] * rden[h];
        }
    }
}

extern "C" void kernel_launch(void* const* d_in, const int* in_sizes, int n_in,
                              void* d_out, int out_size, void* d_ws, size_t ws_size,
                              hipStream_t stream) {
    const float* x  = (const float*)d_in[0];
    const int* seg  = (const int*)d_in[1];
    const float* Wk = (const float*)d_in[11];
    const float* Wq = (const float*)d_in[12];
    float* out = (float*)d_out;

    int* seg_start = (int*)d_ws;                  // [NSEG]
    int* seg_end   = seg_start + NSEG;            // [NSEG]
    float* wxg     = (float*)(seg_end + NSEG);    // [DIM*NH]

    hipLaunchKernelGGL(init_kernel, dim3((NSEG + BLOCK - 1) / BLOCK), dim3(BLOCK),
                       0, stream, Wk, Wq, seg_start, seg_end, wxg);
    hipLaunchKernelGGL(boundary_kernel, dim3((NROWS + BLOCK - 1) / BLOCK), dim3(BLOCK),
                       0, stream, seg, seg_start, seg_end);
    hipLaunchKernelGGL(seg_attn_kernel, dim3(NSEG), dim3(BLOCK), 0, stream,
                       x, seg_start, seg_end, wxg, out);
}

// Round 3
// 142.047 us; speedup vs baseline: 1.7227x; 1.1549x over previous
//
#include <hip/hip_runtime.h>
#include <math.h>

// Output = segment_softmax over logits that depend ONLY on the inputs part of
// combined @ W_k: the agg(segment-mean MLP) contribution is constant within a
// segment and cancels exactly in the segment softmax (shift invariance).
// wx[d][h] = sum_j Wk[d, h*64+j]*Wq[h,j] / 8;  logit[n,h] = x[n,:].wx[:,h];
// per-segment softmax; out[h*N + n].
//
// Round 3: wave-per-segment (no block barriers in hot path), prep kernel
// merges boundary-scan + gap-fill + wx fold (2 launches total).

#define NROWS 500000
#define DIM 40
#define NSEG 2048
#define DOTD 64
#define NH 4
#define BLOCK 256
#define SEG_PER_BLOCK 4      // 4 waves/block, one segment each
#define CACHE_IT 6           // 6*64 = 384 rows fast path (stat max ~300)

// ---- prep: segment bounds (with gap fill for empty segments) + wx fold ----
__global__ __launch_bounds__(BLOCK) void prep_kernel(
    const int* __restrict__ seg,    // [N], sorted
    const float* __restrict__ Wk,   // [168, 256]
    const float* __restrict__ Wq,   // [4, 64]
    int* __restrict__ seg_start,    // [NSEG]
    int* __restrict__ seg_end,      // [NSEG]
    float* __restrict__ wxg)        // [DIM*NH], layout d*4+h
{
    const int tid = (int)threadIdx.x;
    const int n = (int)(blockIdx.x * BLOCK + tid);

    if (blockIdx.x == 0 && tid < DIM * NH) {
        const int d = tid >> 2;
        const int h = tid & 3;
        const float* wkp = Wk + d * (NH * DOTD) + h * DOTD;
        const float* wqp = Wq + h * DOTD;
        float acc = 0.f;
        #pragma unroll
        for (int j = 0; j < DOTD; ++j) acc += wkp[j] * wqp[j];
        wxg[tid] = acc * 0.125f;  // fold 1/sqrt(64)
    }

    if (n < NROWS) {
        const int s = seg[n];
        if (n == 0) {
            seg_start[s] = 0;
            for (int t = 0; t < s; ++t) { seg_start[t] = 0; seg_end[t] = 0; }
        } else {
            const int sp = seg[n - 1];
            if (sp != s) {
                seg_start[s] = n;
                seg_end[sp] = n;
                for (int t = sp + 1; t < s; ++t) { seg_start[t] = n; seg_end[t] = n; }
            }
        }
        if (n == NROWS - 1) {
            seg_end[s] = NROWS;
            for (int t = s + 1; t < NSEG; ++t) { seg_start[t] = NROWS; seg_end[t] = NROWS; }
        }
    }
}

// ---- main: one wave (64 lanes) per segment ----
__global__ __launch_bounds__(BLOCK) void seg_attn_kernel(
    const float* __restrict__ x,          // [N, 40]
    const int* __restrict__ seg_start,
    const int* __restrict__ seg_end,
    const float* __restrict__ wxg,        // [DIM*NH]
    float* __restrict__ out)              // [4, N]
{
    __shared__ float wx[DIM][NH];

    const int tid = (int)threadIdx.x;
    if (tid < DIM * NH) wx[tid >> 2][tid & 3] = wxg[tid];
    __syncthreads();

    const int lane = tid & 63;
    const int s = (int)blockIdx.x * SEG_PER_BLOCK + (tid >> 6);
    const int start = seg_start[s];
    const int end = seg_end[s];
    const int rows = end - start;
    if (rows <= 0) return;               // wave-uniform exit, no barriers below
    const int iters = (rows + 63) >> 6;

    // ---- pass 1: logits + lane-local max ----
    float cache[CACHE_IT][NH];
    float lmax[NH];
    #pragma unroll
    for (int h = 0; h < NH; ++h) lmax[h] = -3.0e38f;

    for (int it = 0; it < iters; ++it) {
        const int i = it * 64 + lane;
        if (i < rows) {
            const float4* xr = (const float4*)(x + (size_t)(start + i) * DIM);
            float acc[NH] = {0.f, 0.f, 0.f, 0.f};
            #pragma unroll
            for (int q = 0; q < DIM / 4; ++q) {
                const float4 v = xr[q];
                #pragma unroll
                for (int h = 0; h < NH; ++h) {
                    acc[h] += v.x * wx[4 * q + 0][h];
                    acc[h] += v.y * wx[4 * q + 1][h];
                    acc[h] += v.z * wx[4 * q + 2][h];
                    acc[h] += v.w * wx[4 * q + 3][h];
                }
            }
            #pragma unroll
            for (int h = 0; h < NH; ++h) {
                if (it < CACHE_IT) cache[it][h] = acc[h];
                lmax[h] = fmaxf(lmax[h], acc[h]);
            }
        }
    }

    // ---- wave max reduce ----
    float m[NH];
    #pragma unroll
    for (int h = 0; h < NH; ++h) {
        float v = lmax[h];
        #pragma unroll
        for (int off = 32; off > 0; off >>= 1) v = fmaxf(v, __shfl_xor(v, off, 64));
        m[h] = v;
    }

    // ---- pass 2: exp + wave sum; cache holds exp(l-m) afterwards ----
    float lsum[NH] = {0.f, 0.f, 0.f, 0.f};
    for (int it = 0; it < iters; ++it) {
        const int i = it * 64 + lane;
        if (i < rows) {
            float e[NH];
            if (it < CACHE_IT) {
                #pragma unroll
                for (int h = 0; h < NH; ++h) {
                    e[h] = __expf(cache[it][h] - m[h]);
                    cache[it][h] = e[h];
                }
            } else {  // fallback: segment longer than 384 rows
                const float4* xr = (const float4*)(x + (size_t)(start + i) * DIM);
                float acc[NH] = {0.f, 0.f, 0.f, 0.f};
                for (int q = 0; q < DIM / 4; ++q) {
                    const float4 v = xr[q];
                    for (int h = 0; h < NH; ++h) {
                        acc[h] += v.x * wx[4 * q + 0][h] + v.y * wx[4 * q + 1][h]
                                + v.z * wx[4 * q + 2][h] + v.w * wx[4 * q + 3][h];
                    }
                }
                for (int h = 0; h < NH; ++h) e[h] = __expf(acc[h] - m[h]);
            }
            #pragma unroll
            for (int h = 0; h < NH; ++h) lsum[h] += e[h];
        }
    }
    float rden[NH];
    #pragma unroll
    for (int h = 0; h < NH; ++h) {
        float v = lsum[h];
        #pragma unroll
        for (int off = 32; off > 0; off >>= 1) v += __shfl_xor(v, off, 64);
        rden[h] = 1.0f / v;
    }

    // ---- pass 3: write normalized outputs (coalesced per h) ----
    for (int it = 0; it < iters; ++it) {
        const int i = it * 64 + lane;
        if (i < rows) {
            float e[NH];
            if (it < CACHE_IT) {
                #pragma unroll
                for (int h = 0; h < NH; ++h) e[h] = cache[it][h];
            } else {
                const float4* xr = (const float4*)(x + (size_t)(start + i) * DIM);
                float acc[NH] = {0.f, 0.f, 0.f, 0.f};
                for (int q = 0; q < DIM / 4; ++q) {
                    const float4 v = xr[q];
                    for (int h = 0; h < NH; ++h) {
                        acc[h] += v.x * wx[4 * q + 0][h] + v.y * wx[4 * q + 1][h]
                                + v.z * wx[4 * q + 2][h] + v.w * wx[4 * q + 3][h];
                    }
                }
                for (int h = 0; h < NH; ++h) e[h] = __expf(acc[h] - m[h]);
            }
            const int n = start + i;
            #pragma unroll
            for (int h = 0; h < NH; ++h) {
                out[(size_t)h * NROWS + n] = e[h] * rden[h];
            }
        }
    }
}

extern "C" void kernel_launch(void* const* d_in, const int* in_sizes, int n_in,
                              void* d_out, int out_size, void* d_ws, size_t ws_size,
                              hipStream_t stream) {
    const float* x  = (const float*)d_in[0];
    const int* seg  = (const int*)d_in[1];
    const float* Wk = (const float*)d_in[11];
    const float* Wq = (const float*)d_in[12];
    float* out = (float*)d_out;

    int* seg_start = (int*)d_ws;                  // [NSEG]
    int* seg_end   = seg_start + NSEG;            // [NSEG]
    float* wxg     = (float*)(seg_end + NSEG);    // [DIM*NH]

    hipLaunchKernelGGL(prep_kernel, dim3((NROWS + BLOCK - 1) / BLOCK), dim3(BLOCK),
                       0, stream, seg, Wk, Wq, seg_start, seg_end, wxg);
    hipLaunchKernelGGL(seg_attn_kernel, dim3(NSEG / SEG_PER_BLOCK), dim3(BLOCK),
                       0, stream, x, seg_start, seg_end, wxg, out);
}